// Round 1
// 359.890 us; speedup vs baseline: 1.0507x; 1.0507x over previous
//
#include <hip/hip_runtime.h>
#include <math.h>

namespace {
constexpr int kB    = 32;
constexpr int kMel  = 128;
constexpr int kT    = 8192;
constexpr int kKeys = 88;
constexpr int kTop  = 15;   // top[13] = 14th largest, top[14] = 15th largest
}

__device__ __forceinline__ void top_insert(float (&top)[kTop], float v) {
#pragma unroll
  for (int j = 0; j < kTop; ++j) {
    const float hi = fmaxf(top[j], v);
    v = fminf(top[j], v);
    top[j] = hi;
  }
}

__global__ __launch_bounds__(256, 4) void key_probs_kernel(
    const float* __restrict__ mel, const int* __restrict__ key_bins,
    float* __restrict__ out) {
  __shared__ int sbins[kKeys];
  const int tid = threadIdx.x;
  if (tid < kKeys) sbins[tid] = key_bins[tid];
  __syncthreads();

  const int t = blockIdx.x * 256 + tid;
  const int b = blockIdx.y;
  const float* melb = mel + (size_t)b * kMel * kT + t;

  // ---- phase A: gather log-domain sums (branchless, fully unrolled, max ILP)
  // e_k = exp(a)*exp(b)*exp(c) is monotone in s_k = a+b+c, so all ranking
  // happens on sums; no exp needed on the fast path.
  float s[kKeys];
#pragma unroll
  for (int k = 0; k < kKeys; ++k) {
    const int m = __builtin_amdgcn_readfirstlane(sbins[k]);  // wave-uniform
    const int r1 = (m < 64) ? 2 * m : m;   // dummy -> same row (L1-hot, in-bounds)
    const int r2 = (m < 43) ? 3 * m : m;
    const float w1 = (m < 64) ? 1.0f : 0.0f;
    const float w2 = (m < 43) ? 1.0f : 0.0f;
    const float v0 = melb[(size_t)m * kT];
    const float v1 = melb[(size_t)r1 * kT];
    const float v2 = melb[(size_t)r2 * kT];
    s[k] = v0 + w1 * v1 + w2 * v2;
  }

  // ---- phase B: select 14th/15th largest of the 88 sums ---------------------
  float top[kTop];
#pragma unroll
  for (int j = 0; j < kTop; ++j) top[j] = -1e30f;  // sums can be negative!
#pragma unroll
  for (int k = 0; k < kKeys; ++k) top_insert(top, s[k]);

  float r74 = top[13];
  const float vstar = top[13];

  // ---- tie-safety scan ------------------------------------------------------
  // key_bins has many duplicate entries (piano semitones < mel spacing below
  // ~400 Hz), so EXACT ties at the 14/15 boundary are common (~30%/lane -> the
  // old `gap < 1e-5` test fired for essentially every wave and ran the f64-exp
  // fallback chip-wide; that was ~100us of pure VALU). An exact tie from a
  // single duplicated bin is provably safe: the reference's products are
  // bit-identical too, thresh == that product, and both sides include all tied
  // elements. Full product-space recompute is needed only when some value
  // within 1e-5 of top[13] is either (a) not exactly equal to it (nonzero
  // near-tie, product rounding could flip the order) or (b) equal but from a
  // different bin (float coincidence; products may differ in rounding).
  bool tieok = true;
  int bmin = 0x3fffffff;
  int bmax = -0x3fffffff;
#pragma unroll
  for (int k = 0; k < kKeys; ++k) {
    const int m = __builtin_amdgcn_readfirstlane(sbins[k]);  // wave-uniform
    const float d = s[k] - vstar;
    const bool c = fabsf(d) < 1e-5f;                // contested (incl. d==0)
    tieok = tieok && (!c || (d == 0.0f));
    bmin = (c && m < bmin) ? m : bmin;
    bmax = (c && m > bmax) ? m : bmax;
  }
  // contested set is never empty: top[13] is itself one of the s[k].
  const bool amb = !(tieok && (bmin == bmax));

  if (amb) {  // rare now: redo this lane in product space, np-compatible exp
    float tp[kTop];
#pragma unroll
    for (int j = 0; j < kTop; ++j) tp[j] = 0.0f;  // products are positive
#pragma unroll
    for (int k = 0; k < kKeys; ++k) {
      const int m = __builtin_amdgcn_readfirstlane(sbins[k]);
      float v = (float)::exp((double)melb[(size_t)m * kT]);
      if (m < 64) v *= (float)::exp((double)melb[(size_t)(2 * m) * kT]);
      if (m < 43) v *= (float)::exp((double)melb[(size_t)(3 * m) * kT]);
      s[k] = v;           // exec-masked: only amb lanes overwritten
      top_insert(tp, v);
    }
    r74 = tp[13];
  }

  // ---- phase C: classify + write both outputs -------------------------------
  float* o0 = out + (size_t)b * kKeys * kT + t;
  float* o1 = o0 + (size_t)kB * kKeys * kT;
#pragma unroll
  for (int k = 0; k < kKeys; ++k) {
    const float r = (s[k] >= r74) ? 1.0f : 0.0f;
    o0[(size_t)k * kT] = r;
    o1[(size_t)k * kT] = r;
  }
}

extern "C" void kernel_launch(void* const* d_in, const int* in_sizes, int n_in,
                              void* d_out, int out_size, void* d_ws, size_t ws_size,
                              hipStream_t stream) {
  const float* mel = (const float*)d_in[0];
  const int* key_bins = (const int*)d_in[1];
  float* out = (float*)d_out;
  dim3 grid(kT / 256, kB);
  key_probs_kernel<<<grid, dim3(256), 0, stream>>>(mel, key_bins, out);
}

// Round 2
// 354.801 us; speedup vs baseline: 1.0658x; 1.0143x over previous
//
#include <hip/hip_runtime.h>
#include <math.h>

namespace {
constexpr int kB    = 32;
constexpr int kMel  = 128;
constexpr int kT    = 8192;
constexpr int kKeys = 88;
constexpr int kTop  = 15;   // top[13] = 14th largest, top[14] = 15th largest
}

__device__ __forceinline__ void top_insert(float (&top)[kTop], float v) {
#pragma unroll
  for (int j = 0; j < kTop; ++j) {
    const float hi = fmaxf(top[j], v);
    v = fminf(top[j], v);
    top[j] = hi;
  }
}

// waves_per_eu(2,4): hard VGPR cap 256, occupancy TARGET 4 waves/EU (<=128
// VGPRs). The grid (1024 blocks = 4 blocks/CU = 16 waves/CU) caps occupancy
// at the 128-VGPR tier anyway, so the compiler's previous choice of 60 VGPRs
// (8-wave tier) bought nothing and forced it to rematerialize s[88] in phase C
// by re-issuing all the loads + serialize phase A behind waitcnts. Letting it
// keep ~128 VGPRs keeps s[] live and the load pipeline deep.
__global__ __attribute__((amdgpu_flat_work_group_size(256, 256),
                          amdgpu_waves_per_eu(2, 4)))
void key_probs_kernel(
    const float* __restrict__ mel, const int* __restrict__ key_bins,
    float* __restrict__ out) {
  __shared__ int sbins[kKeys];
  const int tid = threadIdx.x;
  if (tid < kKeys) sbins[tid] = key_bins[tid];
  __syncthreads();

  const int t = blockIdx.x * 256 + tid;
  const int b = blockIdx.y;
  const float* melb = mel + (size_t)b * kMel * kT + t;

  // ---- phase A: gather log-domain sums (branchless, fully unrolled, max ILP)
  // e_k = exp(a)*exp(b)*exp(c) is monotone in s_k = a+b+c, so all ranking
  // happens on sums; no exp needed on the fast path.
  float s[kKeys];
#pragma unroll
  for (int k = 0; k < kKeys; ++k) {
    const int m = __builtin_amdgcn_readfirstlane(sbins[k]);  // wave-uniform
    const int r1 = (m < 64) ? 2 * m : m;   // dummy -> same row (L1-hot, in-bounds)
    const int r2 = (m < 43) ? 3 * m : m;
    const float w1 = (m < 64) ? 1.0f : 0.0f;
    const float w2 = (m < 43) ? 1.0f : 0.0f;
    const float v0 = melb[(size_t)m * kT];
    const float v1 = melb[(size_t)r1 * kT];
    const float v2 = melb[(size_t)r2 * kT];
    s[k] = v0 + w1 * v1 + w2 * v2;
  }

  // ---- phase B: select 14th/15th largest of the 88 sums ---------------------
  float top[kTop];
#pragma unroll
  for (int j = 0; j < kTop; ++j) top[j] = -1e30f;  // sums can be negative!
#pragma unroll
  for (int k = 0; k < kKeys; ++k) top_insert(top, s[k]);

  float r74 = top[13];
  const float vstar = top[13];

  // ---- tie-safety scan ------------------------------------------------------
  // key_bins has many duplicate entries (piano semitones < mel spacing below
  // ~400 Hz), so EXACT ties at the 14/15 boundary are common. An exact tie
  // from a single duplicated bin is provably safe: the reference's products
  // are bit-identical too, thresh == that product, and both sides include all
  // tied elements. Full product-space recompute is needed only when some value
  // within 1e-5 of top[13] is either (a) not exactly equal to it (nonzero
  // near-tie, product rounding could flip the order) or (b) equal but from a
  // different bin (float coincidence; products may differ in rounding).
  bool tieok = true;
  int bmin = 0x3fffffff;
  int bmax = -0x3fffffff;
#pragma unroll
  for (int k = 0; k < kKeys; ++k) {
    const int m = __builtin_amdgcn_readfirstlane(sbins[k]);  // wave-uniform
    const float d = s[k] - vstar;
    const bool c = fabsf(d) < 1e-5f;                // contested (incl. d==0)
    tieok = tieok && (!c || (d == 0.0f));
    bmin = (c && m < bmin) ? m : bmin;
    bmax = (c && m > bmax) ? m : bmax;
  }
  // contested set is never empty: top[13] is itself one of the s[k].
  const bool amb = !(tieok && (bmin == bmax));

  if (amb) {  // rare: redo this lane in product space, np-compatible exp
    float tp[kTop];
#pragma unroll
    for (int j = 0; j < kTop; ++j) tp[j] = 0.0f;  // products are positive
#pragma unroll
    for (int k = 0; k < kKeys; ++k) {
      const int m = __builtin_amdgcn_readfirstlane(sbins[k]);
      float v = (float)::exp((double)melb[(size_t)m * kT]);
      if (m < 64) v *= (float)::exp((double)melb[(size_t)(2 * m) * kT]);
      if (m < 43) v *= (float)::exp((double)melb[(size_t)(3 * m) * kT]);
      s[k] = v;           // exec-masked: only amb lanes overwritten
      top_insert(tp, v);
    }
    r74 = tp[13];
  }

  // ---- phase C: classify + write both outputs -------------------------------
  // Streaming writes, never re-read: nontemporal keeps them from evicting the
  // mel rows in L1/L2.
  float* o0 = out + (size_t)b * kKeys * kT + t;
  float* o1 = o0 + (size_t)kB * kKeys * kT;
#pragma unroll
  for (int k = 0; k < kKeys; ++k) {
    const float r = (s[k] >= r74) ? 1.0f : 0.0f;
    __builtin_nontemporal_store(r, &o0[(size_t)k * kT]);
    __builtin_nontemporal_store(r, &o1[(size_t)k * kT]);
  }
}

extern "C" void kernel_launch(void* const* d_in, const int* in_sizes, int n_in,
                              void* d_out, int out_size, void* d_ws, size_t ws_size,
                              hipStream_t stream) {
  const float* mel = (const float*)d_in[0];
  const int* key_bins = (const int*)d_in[1];
  float* out = (float*)d_out;
  dim3 grid(kT / 256, kB);
  key_probs_kernel<<<grid, dim3(256), 0, stream>>>(mel, key_bins, out);
}

// Round 3
// 294.170 us; speedup vs baseline: 1.2855x; 1.2061x over previous
//
#include <hip/hip_runtime.h>
#include <math.h>

namespace {
constexpr int kB    = 32;
constexpr int kMel  = 128;
constexpr int kT    = 8192;
constexpr int kKeys = 88;
constexpr int kTop  = 15;   // top[13] = 14th largest, top[14] = 15th largest
constexpr int kD    = 57;   // distinct mel bins among the 88 keys

// key_bins is a DETERMINISTIC function of the mel filterbank geometry (the
// only randomness in setup_inputs feeds mel, not key_bins). Hardcoding the
// table lets the compiler (a) load each distinct mel row once (89 loads vs
// ~390 with the runtime-indexed gather + phase-C remat), (b) CSE the 88 keys
// down to 57 distinct sums so the live set fits in registers. The table is
// VERIFIED against the real key_bins input per block; any mismatch falls back
// to the generic data-driven path — a wrong entry costs speed, never
// correctness.
constexpr int kDistM[kD] = {
    1,  2,  3,  4,  5,  6,  7,  8,  9, 10, 11, 12, 13, 14, 15, 16, 17,
   19, 20, 21, 22, 23, 25, 26, 28, 29, 31, 33, 35, 37, 39, 42,
   44, 46, 49, 51, 53, 56, 58, 60, 63, 65, 68, 70, 72, 75, 77, 79,
   82, 84, 86, 89, 91, 93, 96, 98, 101};
constexpr int kCnt[kD] = {
    5, 9, 6, 4, 3, 3, 3, 2, 2, 2, 1, 2, 1, 1, 1, 1, 2,
    1, 1, 1, 1, 1, 1, 1, 1, 1, 1, 1, 1, 1, 1, 1,
    1, 1, 1, 1, 1, 1, 1, 1, 1, 1, 1, 1, 1, 1, 1, 1,
    1, 1, 1, 1, 1, 1, 1, 1, 1};
constexpr int kIdx[kKeys] = {
    0, 0, 0, 0, 0,
    1, 1, 1, 1, 1, 1, 1, 1, 1,
    2, 2, 2, 2, 2, 2,
    3, 3, 3, 3,
    4, 4, 4,
    5, 5, 5,
    6, 6, 6,
    7, 7,
    8, 8,
    9, 9,
   10,
   11, 11,
   12, 13, 14, 15,
   16, 16,
   17, 18, 19, 20, 21, 22, 23, 24, 25, 26, 27, 28, 29, 30, 31,
   32, 33, 34, 35, 36, 37, 38, 39, 40, 41, 42, 43, 44, 45, 46, 47,
   48, 49, 50, 51, 52, 53, 54, 55, 56};
}

__device__ __forceinline__ void top_insert(float (&top)[kTop], float v) {
#pragma unroll
  for (int j = 0; j < kTop; ++j) {
    const float hi = fmaxf(top[j], v);
    v = fminf(top[j], v);
    top[j] = hi;
  }
}

__global__ __launch_bounds__(256, 4) void key_probs_kernel(
    const float* __restrict__ mel, const int* __restrict__ key_bins,
    float* __restrict__ out) {
  __shared__ int sbins[kKeys];
  const int tid = threadIdx.x;
  int ok = 1;
  if (tid < kKeys) {
    const int bin = key_bins[tid];
    sbins[tid] = bin;
    ok = (bin == kDistM[kIdx[tid]]);
  }
  const int allok = __syncthreads_and(ok);

  const int t = blockIdx.x * 256 + tid;
  const int b = blockIdx.y;
  const float* melb = mel + (size_t)b * kMel * kT + t;
  float* o0 = out + (size_t)b * kKeys * kT + t;
  float* o1 = o0 + (size_t)kB * kKeys * kT;

  if (allok) {
    // ================= FAST PATH: compile-time bins =================
    // phase A: one load per distinct row (89 rows), 57 distinct sums.
    // e_k = exp(a)exp(b)exp(c) is monotone in a+b+c -> rank on sums.
    float sd[kD];
#pragma unroll
    for (int j = 0; j < kD; ++j) {
      const int m = kDistM[j];
      float v = melb[(size_t)m * kT];
      if (2 * m < kMel) v += melb[(size_t)(2 * m) * kT];
      if (3 * m < kMel) v += melb[(size_t)(3 * m) * kT];
      sd[j] = v;
    }

    // phase B: weighted 14th largest (each distinct value counts kCnt times)
    float top[kTop];
#pragma unroll
    for (int j = 0; j < kTop; ++j) top[j] = -1e30f;  // sums can be negative
#pragma unroll
    for (int j = 0; j < kD; ++j) {
#pragma unroll
      for (int c = 0; c < kCnt[j]; ++c) top_insert(top, sd[j]);
    }

    float r74 = top[13];
    const float vstar = top[13];

    // tie safety: exact ties among copies of ONE distinct bin are safe (the
    // reference's products are bit-identical and thresh == that product).
    // Ambiguous only if some distinct value is within 1e-5 of vstar but not
    // exactly equal (product-space rounding could reorder), or >=2 DISTINCT
    // bins are exactly equal to vstar (float coincidence).
    int neq = 0;
    bool near_ne = false;
#pragma unroll
    for (int j = 0; j < kD; ++j) {
      const float d = sd[j] - vstar;
      const bool c = fabsf(d) < 1e-5f;
      near_ne = near_ne || (c && (d != 0.0f));
      neq += (c && (d == 0.0f)) ? 1 : 0;
    }
    const bool amb = near_ne || (neq > 1);

    if (amb) {  // rare: redo this lane in product space, np-compatible exp
      float tp[kTop];
#pragma unroll
      for (int j = 0; j < kTop; ++j) tp[j] = 0.0f;  // products positive
#pragma unroll
      for (int j = 0; j < kD; ++j) {
        const int m = kDistM[j];
        float v = (float)::exp((double)melb[(size_t)m * kT]);
        if (2 * m < kMel) v *= (float)::exp((double)melb[(size_t)(2 * m) * kT]);
        if (3 * m < kMel) v *= (float)::exp((double)melb[(size_t)(3 * m) * kT]);
        sd[j] = v;  // exec-masked: only amb lanes overwritten
#pragma unroll
        for (int c = 0; c < kCnt[j]; ++c) top_insert(tp, v);
      }
      r74 = tp[13];
    }

    // phase C: 57 compares (CSE'd), 176 streaming stores
#pragma unroll
    for (int k = 0; k < kKeys; ++k) {
      const float r = (sd[kIdx[k]] >= r74) ? 1.0f : 0.0f;
      __builtin_nontemporal_store(r, &o0[(size_t)k * kT]);
      __builtin_nontemporal_store(r, &o1[(size_t)k * kT]);
    }
    return;
  }

  // ================= GENERIC FALLBACK: data-driven bins =================
  // (proven R2 path; taken only if the hardcoded table mismatches)
  float s[kKeys];
#pragma unroll
  for (int k = 0; k < kKeys; ++k) {
    const int m = __builtin_amdgcn_readfirstlane(sbins[k]);  // wave-uniform
    const int r1 = (m < 64) ? 2 * m : m;   // dummy -> same row (L1-hot)
    const int r2 = (m < 43) ? 3 * m : m;
    const float w1 = (m < 64) ? 1.0f : 0.0f;
    const float w2 = (m < 43) ? 1.0f : 0.0f;
    const float v0 = melb[(size_t)m * kT];
    const float v1 = melb[(size_t)r1 * kT];
    const float v2 = melb[(size_t)r2 * kT];
    s[k] = v0 + w1 * v1 + w2 * v2;
  }

  float top[kTop];
#pragma unroll
  for (int j = 0; j < kTop; ++j) top[j] = -1e30f;
#pragma unroll
  for (int k = 0; k < kKeys; ++k) top_insert(top, s[k]);

  float r74 = top[13];
  const float vstar = top[13];

  bool tieok = true;
  int bmin = 0x3fffffff;
  int bmax = -0x3fffffff;
#pragma unroll
  for (int k = 0; k < kKeys; ++k) {
    const int m = __builtin_amdgcn_readfirstlane(sbins[k]);
    const float d = s[k] - vstar;
    const bool c = fabsf(d) < 1e-5f;
    tieok = tieok && (!c || (d == 0.0f));
    bmin = (c && m < bmin) ? m : bmin;
    bmax = (c && m > bmax) ? m : bmax;
  }
  const bool amb = !(tieok && (bmin == bmax));

  if (amb) {
    float tp[kTop];
#pragma unroll
    for (int j = 0; j < kTop; ++j) tp[j] = 0.0f;
#pragma unroll
    for (int k = 0; k < kKeys; ++k) {
      const int m = __builtin_amdgcn_readfirstlane(sbins[k]);
      float v = (float)::exp((double)melb[(size_t)m * kT]);
      if (m < 64) v *= (float)::exp((double)melb[(size_t)(2 * m) * kT]);
      if (m < 43) v *= (float)::exp((double)melb[(size_t)(3 * m) * kT]);
      s[k] = v;
      top_insert(tp, v);
    }
    r74 = tp[13];
  }

#pragma unroll
  for (int k = 0; k < kKeys; ++k) {
    const float r = (s[k] >= r74) ? 1.0f : 0.0f;
    __builtin_nontemporal_store(r, &o0[(size_t)k * kT]);
    __builtin_nontemporal_store(r, &o1[(size_t)k * kT]);
  }
}

extern "C" void kernel_launch(void* const* d_in, const int* in_sizes, int n_in,
                              void* d_out, int out_size, void* d_ws, size_t ws_size,
                              hipStream_t stream) {
  const float* mel = (const float*)d_in[0];
  const int* key_bins = (const int*)d_in[1];
  float* out = (float*)d_out;
  dim3 grid(kT / 256, kB);
  key_probs_kernel<<<grid, dim3(256), 0, stream>>>(mel, key_bins, out);
}